// Round 11
// baseline (419.746 us; speedup 1.0000x reference)
//
#include <hip/hip_runtime.h>
#include <hip/hip_bf16.h>
#include <math.h>

// Problem constants (fixed by the reference)
#define NN 50000
#define NE 800000
#define NPAD 50048   // 782 * 64 — tail-free GEMM tiles
#define NB_SCAN 196  // ceil(NN/256)

typedef unsigned short u16;
typedef unsigned int u32;
typedef __attribute__((ext_vector_type(8))) short short8;   // 8 bf16 (MFMA A/B frag)
typedef __attribute__((ext_vector_type(4))) float float4v;  // MFMA C/D frag

__device__ __forceinline__ float us2f(u16 u) { return __uint_as_float(((unsigned)u) << 16); }
__device__ __forceinline__ float blo(u32 u) { return __uint_as_float(u << 16); }
__device__ __forceinline__ float bhi(u32 u) { return __uint_as_float(u & 0xffff0000u); }
__device__ __forceinline__ u16 f2us(float f) {   // fp32 -> bf16 RNE
    unsigned x = __float_as_uint(f);
    return (u16)((x + 0x7FFFu + ((x >> 16) & 1u)) >> 16);
}
// tanh-gelu via sigmoid identity: 0.5*(1+tanh(u)) = sigmoid(2u)
__device__ __forceinline__ float gelu_f(float x) {
    float p = x * x;
    float t = x * fmaf(p, 0.0713548162726f, 1.5957691216057308f);  // 2u
    float e = __expf(-t);
    return x * __builtin_amdgcn_rcpf(1.0f + e);
}
// intra-wave LDS ordering fence (wave-private LDS regions; no cross-wave barrier)
__device__ __forceinline__ void lds_fence() {
    asm volatile("s_waitcnt lgkmcnt(0)" ::: "memory");
}

// ---- permuted-weight MFMA: WP holds B-frags contiguous per (tile, kblock) ----
// WP u16 layout: tile*2048 + q*512 + l*8 + j  <=>  W[tile*16 + (l&15)][q*32 + (l>>4)*8 + j]
__device__ __forceinline__ float4v mfma4p(const u16* __restrict__ WP, int tile, int l,
                                          short8 a0, short8 a1, short8 a2, short8 a3) {
    const short8* wp = (const short8*)WP + (size_t)tile * 256 + l;
    short8 b0 = wp[0], b1 = wp[64], b2 = wp[128], b3 = wp[192];
    float4v acc = {0.f, 0.f, 0.f, 0.f};
    acc = __builtin_amdgcn_mfma_f32_16x16x32_bf16(a0, b0, acc, 0, 0, 0);
    acc = __builtin_amdgcn_mfma_f32_16x16x32_bf16(a1, b1, acc, 0, 0, 0);
    acc = __builtin_amdgcn_mfma_f32_16x16x32_bf16(a2, b2, acc, 0, 0, 0);
    acc = __builtin_amdgcn_mfma_f32_16x16x32_bf16(a3, b3, acc, 0, 0, 0);
    return acc;
}

// ---------------- CSR build ----------------

__global__ void k_hist(const int* __restrict__ dstv, int* __restrict__ deg) {
    int e = blockIdx.x * blockDim.x + threadIdx.x;
    if (e < NE) atomicAdd(&deg[dstv[e]], 1);
}

__global__ __launch_bounds__(256) void k_scan1(const int* __restrict__ deg,
                                               int* __restrict__ rowstart,
                                               int* __restrict__ bsum) {
    __shared__ int wtot[4];
    int i = blockIdx.x * 256 + threadIdx.x;
    int lane = threadIdx.x & 63, w = threadIdx.x >> 6;
    int v = (i < NN) ? deg[i] : 0;
    int incl = v;
#pragma unroll
    for (int d = 1; d < 64; d <<= 1) {
        int tv = __shfl_up(incl, d);
        if (lane >= d) incl += tv;
    }
    if (lane == 63) wtot[w] = incl;
    __syncthreads();
    if (threadIdx.x == 0) {
        int s = 0;
#pragma unroll
        for (int j = 0; j < 4; ++j) { int t = wtot[j]; wtot[j] = s; s += t; }
        bsum[blockIdx.x] = s;
    }
    __syncthreads();
    if (i < NN) rowstart[i] = incl - v + wtot[w];
}

__global__ __launch_bounds__(256) void k_scan2(int* __restrict__ bsum) {
    __shared__ int wtot[4];
    int t = threadIdx.x;
    int lane = t & 63, w = t >> 6;
    int v = (t < NB_SCAN) ? bsum[t] : 0;
    int incl = v;
#pragma unroll
    for (int d = 1; d < 64; d <<= 1) {
        int tv = __shfl_up(incl, d);
        if (lane >= d) incl += tv;
    }
    if (lane == 63) wtot[w] = incl;
    __syncthreads();
    if (t == 0) {
        int s = 0;
#pragma unroll
        for (int j = 0; j < 4; ++j) { int tt = wtot[j]; wtot[j] = s; s += tt; }
    }
    __syncthreads();
    if (t < NB_SCAN) bsum[t] = incl - v + wtot[w];
}

__global__ void k_scan3(const int* __restrict__ bsum, int* __restrict__ rowstart,
                        int* __restrict__ cursor) {
    int i = blockIdx.x * 256 + threadIdx.x;
    if (i < NN) {
        int v = rowstart[i] + bsum[blockIdx.x];
        rowstart[i] = v;
        cursor[i] = v;
    }
    if (i == 0) rowstart[NN] = NE;
}

__global__ void k_scatter(const int* __restrict__ srcv, const int* __restrict__ dstv,
                          const float* __restrict__ eattr, int* __restrict__ cursor,
                          int4* __restrict__ rec) {
    int e = blockIdx.x * blockDim.x + threadIdx.x;
    if (e >= NE) return;
    int dst = dstv[e];
    int pos = atomicAdd(&cursor[dst], 1);
    int4 r;
    r.x = srcv[e];
    r.y = __float_as_int(eattr[e * 3 + 0]);
    r.z = __float_as_int(eattr[e * 3 + 1]);
    r.w = __float_as_int(eattr[e * 3 + 2]);
    rec[pos] = r;
}

// ---------------- weight fp32 -> bf16, permuted into B-frag order ----------------

struct CvtEnt { const float* s; u16* d; int n; };
struct CvtTab { CvtEnt e[14]; };
__global__ void k_cvt_w(CvtTab tab) {
    CvtEnt E = tab.e[blockIdx.x >> 3];
    int chunk = blockIdx.x & 7;
    int per = E.n >> 3;
    int lo = chunk * per, hi = lo + per;
    for (int o = lo + threadIdx.x; o < hi; o += blockDim.x) {
        int tile = o >> 11;
        int q = (o >> 9) & 3;
        int l = (o >> 3) & 63;
        int j = o & 7;
        int row = tile * 16 + (l & 15);
        int col = q * 32 + (l >> 4) * 8 + j;
        E.d[o] = f2us(E.s[row * 128 + col]);
    }
}

// =============== barrier-free, wave-private GEMM chain kernels ===============

__device__ __forceinline__ void stage_plain(u16* buf, int kb, int m, int tt, float4v acc) {
#pragma unroll
    for (int r = 0; r < 4; ++r) buf[(kb * 4 + r) * 136 + tt * 16 + m] = f2us(acc[r]);
}
__device__ __forceinline__ void store128(const u16* buf, u16* dst, int r0w, int coff, int l) {
#pragma unroll
    for (int it = 0; it < 4; ++it) {
        int j = it * 64 + l;
        int row = j >> 4, col = (j & 15) * 8;
        *(uint4*)(dst + (size_t)(r0w + row) * 512 + coff + col) = *(const uint4*)&buf[row * 136 + col];
    }
}
__device__ __forceinline__ void read_frags(const u16* buf, int m, int kb,
                                           short8& f0, short8& f1, short8& f2, short8& f3) {
    const u16* p = buf + m * 136 + kb * 8;
    f0 = *(const short8*)(p);
    f1 = *(const short8*)(p + 32);
    f2 = *(const short8*)(p + 64);
    f3 = *(const short8*)(p + 96);
}

// kv staging: col c -> k at (c>>2)*8+(c&3), v at (c>>2)*8+4+(c&3)
// i.e. groups {k[4p..4p+3], v[4p..4p+3]} — conv lane li reads 32B at 128+li*16.

// ---------------- layer-1 QKVS GEMM, column-split (grid.y=2) ----------------
// y==0: q (tiles 0..7, cols 0..127) + kv-lo (k 8..11 / v 16..19, cols 128..255)
// y==1: kv-hi (k 12..15 / v 20..23, cols 256..383) + s (24..31, cols 384..511)

__global__ __launch_bounds__(256, 4) void k_qkvs1(const float* __restrict__ Ain,
                                                  const u16* __restrict__ W,
                                                  u16* __restrict__ QKVS) {
    __shared__ u16 tile[4][16 * 136];
    int tid = threadIdx.x;
    int l = tid & 63, w = tid >> 6, m = l & 15, kb = l >> 4;
    int r0w = blockIdx.x * 64 + w * 16;
    u16* my = tile[w];

    short8 a0, a1, a2, a3;
    {
        const float* ap = Ain + (size_t)(r0w + m) * 128;
        bool ok = (r0w + m) < NN;
        short8* dsts[4] = {&a0, &a1, &a2, &a3};
#pragma unroll
        for (int i = 0; i < 4; ++i) {
            short8 r;
            if (ok) {
                const float* p = ap + (kb + i * 4) * 8;
                float4 f0 = *(const float4*)p;
                float4 f1 = *(const float4*)(p + 4);
                r[0]=(short)f2us(f0.x); r[1]=(short)f2us(f0.y); r[2]=(short)f2us(f0.z); r[3]=(short)f2us(f0.w);
                r[4]=(short)f2us(f1.x); r[5]=(short)f2us(f1.y); r[6]=(short)f2us(f1.z); r[7]=(short)f2us(f1.w);
            } else {
#pragma unroll
                for (int j = 0; j < 8; ++j) r[j] = 0;
            }
            *dsts[i] = r;
        }
    }

    if (blockIdx.y == 0) {
        // ---- q (tiles 0..7) ----
#pragma unroll
        for (int tt = 0; tt < 8; ++tt) stage_plain(my, kb, m, tt, mfma4p(W, tt, l, a0, a1, a2, a3));
        lds_fence();
        store128(my, QKVS, r0w, 0, l);
        lds_fence();
        // ---- kv-lo: k tiles 8..11 + v tiles 16..19 ----
#pragma unroll
        for (int tt = 0; tt < 4; ++tt) {
            float4v acc = mfma4p(W, 8 + tt, l, a0, a1, a2, a3);
            int c = tt * 32 + 8 * (m >> 2) + (m & 3);
#pragma unroll
            for (int r = 0; r < 4; ++r) my[(kb * 4 + r) * 136 + c] = f2us(acc[r]);
        }
#pragma unroll
        for (int tt = 0; tt < 4; ++tt) {
            float4v acc = mfma4p(W, 16 + tt, l, a0, a1, a2, a3);
            int c = tt * 32 + 8 * (m >> 2) + (m & 3) + 4;
#pragma unroll
            for (int r = 0; r < 4; ++r) my[(kb * 4 + r) * 136 + c] = f2us(acc[r]);
        }
        lds_fence();
        store128(my, QKVS, r0w, 128, l);
    } else {
        // ---- kv-hi: k tiles 12..15 + v tiles 20..23 ----
#pragma unroll
        for (int tt = 0; tt < 4; ++tt) {
            float4v acc = mfma4p(W, 12 + tt, l, a0, a1, a2, a3);
            int c = tt * 32 + 8 * (m >> 2) + (m & 3);
#pragma unroll
            for (int r = 0; r < 4; ++r) my[(kb * 4 + r) * 136 + c] = f2us(acc[r]);
        }
#pragma unroll
        for (int tt = 0; tt < 4; ++tt) {
            float4v acc = mfma4p(W, 20 + tt, l, a0, a1, a2, a3);
            int c = tt * 32 + 8 * (m >> 2) + (m & 3) + 4;
#pragma unroll
            for (int r = 0; r < 4; ++r) my[(kb * 4 + r) * 136 + c] = f2us(acc[r]);
        }
        lds_fence();
        store128(my, QKVS, r0w, 256, l);
        lds_fence();
        // ---- s (tiles 24..31) ----
#pragma unroll
        for (int tt = 0; tt < 8; ++tt) stage_plain(my, kb, m, tt, mfma4p(W, 24 + tt, l, a0, a1, a2, a3));
        lds_fence();
        store128(my, QKVS, r0w, 384, l);
    }
}

// ---------------- fused MLP + next-layer QKVS, column-split (grid.y=2) ----------------
// MLP prefix (H2) computed in both halves; QKVS sections split as in k_qkvs1.

__global__ __launch_bounds__(256, 4) void k_mlp_qkvs(const u16* __restrict__ Ain,
                                                     const u16* __restrict__ Wm,
                                                     const float* __restrict__ bias1,
                                                     const float* __restrict__ bias2,
                                                     const u16* __restrict__ Wq,
                                                     u16* __restrict__ QKVS) {
    __shared__ u16 shb[4][16 * 136];
    __shared__ u16 t1b[4][16 * 136];
    int tid = threadIdx.x;
    int l = tid & 63, w = tid >> 6, m = l & 15, kb = l >> 4;
    int r0w = blockIdx.x * 64 + w * 16;
    u16* sh = shb[w];
    u16* t1 = t1b[w];

    const short8* arow = (const short8*)(Ain + (size_t)(r0w + m) * 128);
    short8 a0 = arow[kb], a1 = arow[kb + 4], a2 = arow[kb + 8], a3 = arow[kb + 12];
    {   // stage A (residual source), linear rows
        u16* p = sh + m * 136 + kb * 8;
        *(short8*)(p) = a0;
        *(short8*)(p + 32) = a1;
        *(short8*)(p + 64) = a2;
        *(short8*)(p + 96) = a3;
    }
    // GEMM1 -> t1 (gelu)
#pragma unroll
    for (int tt = 0; tt < 8; ++tt) {
        float4v acc = mfma4p(Wm, tt, l, a0, a1, a2, a3);
        float bv = bias1[tt * 16 + m];
#pragma unroll
        for (int r = 0; r < 4; ++r)
            t1[(kb * 4 + r) * 136 + tt * 16 + m] = f2us(gelu_f(acc[r] + bv));
    }
    lds_fence();
    short8 c0, c1, c2, c3;
    read_frags(t1, m, kb, c0, c1, c2, c3);
    // GEMM2 + residual -> sh becomes H2 (owner-lane RMW)
#pragma unroll
    for (int tt = 0; tt < 8; ++tt) {
        float4v acc = mfma4p(Wm + 16384, tt, l, c0, c1, c2, c3);
        float bv = bias2[tt * 16 + m];
#pragma unroll
        for (int r = 0; r < 4; ++r) {
            int idx = (kb * 4 + r) * 136 + tt * 16 + m;
            sh[idx] = f2us(gelu_f(acc[r] + bv) + us2f(sh[idx]));
        }
    }
    lds_fence();
    short8 h0, h1, h2, h3;
    read_frags(sh, m, kb, h0, h1, h2, h3);

    if (blockIdx.y == 0) {
        // ---- q (tiles 0..7) ----
#pragma unroll
        for (int tt = 0; tt < 8; ++tt) stage_plain(t1, kb, m, tt, mfma4p(Wq, tt, l, h0, h1, h2, h3));
        lds_fence();
        store128(t1, QKVS, r0w, 0, l);
        lds_fence();
        // ---- kv-lo ----
#pragma unroll
        for (int tt = 0; tt < 4; ++tt) {
            float4v acc = mfma4p(Wq, 8 + tt, l, h0, h1, h2, h3);
            int c = tt * 32 + 8 * (m >> 2) + (m & 3);
#pragma unroll
            for (int r = 0; r < 4; ++r) t1[(kb * 4 + r) * 136 + c] = f2us(acc[r]);
        }
#pragma unroll
        for (int tt = 0; tt < 4; ++tt) {
            float4v acc = mfma4p(Wq, 16 + tt, l, h0, h1, h2, h3);
            int c = tt * 32 + 8 * (m >> 2) + (m & 3) + 4;
#pragma unroll
            for (int r = 0; r < 4; ++r) t1[(kb * 4 + r) * 136 + c] = f2us(acc[r]);
        }
        lds_fence();
        store128(t1, QKVS, r0w, 128, l);
    } else {
        // ---- kv-hi ----
#pragma unroll
        for (int tt = 0; tt < 4; ++tt) {
            float4v acc = mfma4p(Wq, 12 + tt, l, h0, h1, h2, h3);
            int c = tt * 32 + 8 * (m >> 2) + (m & 3);
#pragma unroll
            for (int r = 0; r < 4; ++r) t1[(kb * 4 + r) * 136 + c] = f2us(acc[r]);
        }
#pragma unroll
        for (int tt = 0; tt < 4; ++tt) {
            float4v acc = mfma4p(Wq, 20 + tt, l, h0, h1, h2, h3);
            int c = tt * 32 + 8 * (m >> 2) + (m & 3) + 4;
#pragma unroll
            for (int r = 0; r < 4; ++r) t1[(kb * 4 + r) * 136 + c] = f2us(acc[r]);
        }
        lds_fence();
        store128(t1, QKVS, r0w, 256, l);
        lds_fence();
        // ---- s (tiles 24..31) ----
#pragma unroll
        for (int tt = 0; tt < 8; ++tt) stage_plain(t1, kb, m, tt, mfma4p(Wq, 24 + tt, l, h0, h1, h2, h3));
        lds_fence();
        store128(t1, QKVS, r0w, 384, l);
    }
}

// ---------------- fused MLP + final MLP (unchanged) ----------------

__global__ __launch_bounds__(256, 4) void k_mlp_final(const u16* __restrict__ Ain,
                                                      const u16* __restrict__ Wm,
                                                      const float* __restrict__ bias1,
                                                      const float* __restrict__ bias2,
                                                      const u16* __restrict__ Wf,
                                                      const float* __restrict__ bf1,
                                                      const float* __restrict__ bf2,
                                                      float* __restrict__ outp) {
    __shared__ u16 shb[4][16 * 136];
    __shared__ u16 t1b[4][16 * 136];
    int tid = threadIdx.x;
    int l = tid & 63, w = tid >> 6, m = l & 15, kb = l >> 4;
    int r0w = blockIdx.x * 64 + w * 16;
    u16* sh = shb[w];
    u16* t1 = t1b[w];

    const short8* arow = (const short8*)(Ain + (size_t)(r0w + m) * 128);
    short8 a0 = arow[kb], a1 = arow[kb + 4], a2 = arow[kb + 8], a3 = arow[kb + 12];
    {
        u16* p = sh + m * 136 + kb * 8;
        *(short8*)(p) = a0;
        *(short8*)(p + 32) = a1;
        *(short8*)(p + 64) = a2;
        *(short8*)(p + 96) = a3;
    }
#pragma unroll
    for (int tt = 0; tt < 8; ++tt) {
        float4v acc = mfma4p(Wm, tt, l, a0, a1, a2, a3);
        float bv = bias1[tt * 16 + m];
#pragma unroll
        for (int r = 0; r < 4; ++r)
            t1[(kb * 4 + r) * 136 + tt * 16 + m] = f2us(gelu_f(acc[r] + bv));
    }
    lds_fence();
    short8 c0, c1, c2, c3;
    read_frags(t1, m, kb, c0, c1, c2, c3);
#pragma unroll
    for (int tt = 0; tt < 8; ++tt) {
        float4v acc = mfma4p(Wm + 16384, tt, l, c0, c1, c2, c3);
        float bv = bias2[tt * 16 + m];
#pragma unroll
        for (int r = 0; r < 4; ++r) {
            int idx = (kb * 4 + r) * 136 + tt * 16 + m;
            sh[idx] = f2us(gelu_f(acc[r] + bv) + us2f(sh[idx]));
        }
    }
    lds_fence();
    short8 h0, h1, h2, h3;
    read_frags(sh, m, kb, h0, h1, h2, h3);
    // G3 = gelu(H4@Wf1+bf1) -> t1
#pragma unroll
    for (int tt = 0; tt < 8; ++tt) {
        float4v acc = mfma4p(Wf, tt, l, h0, h1, h2, h3);
        float bv = bf1[tt * 16 + m];
#pragma unroll
        for (int r = 0; r < 4; ++r)
            t1[(kb * 4 + r) * 136 + tt * 16 + m] = f2us(gelu_f(acc[r] + bv));
    }
    lds_fence();
    short8 f0, f1, f2, f3;
    read_frags(t1, m, kb, f0, f1, f2, f3);
    lds_fence();
    // G4 = gelu(G3@Wf2+bf2), 64 cols -> t1
#pragma unroll
    for (int tt = 0; tt < 4; ++tt) {
        float4v acc = mfma4p(Wf + 16384, tt, l, f0, f1, f2, f3);
        float bv = bf2[tt * 16 + m];
#pragma unroll
        for (int r = 0; r < 4; ++r)
            t1[(kb * 4 + r) * 136 + tt * 16 + m] = f2us(gelu_f(acc[r] + bv));
    }
    lds_fence();
#pragma unroll
    for (int it = 0; it < 2; ++it) {
        int j = it * 64 + l;
        int row = j >> 3, col = (j & 7) * 8;
        int grow = r0w + row;
        if (grow < NN) {
            uint4 pk = *(const uint4*)&t1[row * 136 + col];
            const u16* pv = (const u16*)&pk;
            float* po = outp + (size_t)grow * 64 + col;
            float4 o0 = {us2f(pv[0]), us2f(pv[1]), us2f(pv[2]), us2f(pv[3])};
            float4 o1 = {us2f(pv[4]), us2f(pv[5]), us2f(pv[6]), us2f(pv[7])};
            *(float4*)po = o0;
            *(float4*)(po + 4) = o1;
        }
    }
}

// ---------------- TransformerConv: 4 edges/wave, 8 cols/lane, pipelined gather ----------------
// 1 wave per node. Quarter q = l>>4 handles edges e0+q, e0+q+4, ...; lane li = l&15
// covers cols li*8..li*8+7 (head = li>>2; head dot-reduce = shfl_xor 1,2).
// Pipeline: rec 2 iterations ahead, kv 1 ahead (clamped loads, validity via p=0).
// q prescaled by 1/sqrt(32) (g inherits scale). No-max softmax (exp clamp 80).

__global__ __launch_bounds__(256) void k_conv(const int* __restrict__ rowstart,
                                              const int4* __restrict__ rec,
                                              const u16* __restrict__ qkvs,
                                              const float* __restrict__ We,
                                              u16* __restrict__ out) {
    int n = blockIdx.x * 4 + (threadIdx.x >> 6);
    int l = threadIdx.x & 63;
    int quarter = l >> 4;
    int li = l & 15;
    int c0 = li * 8;
    const u16* qrow = qkvs + (size_t)n * 512;
    uint4 qu = *(const uint4*)(qrow + c0);
    const float SC = 0.17677669529663687f;
    float q0 = blo(qu.x) * SC, q1 = bhi(qu.x) * SC, q2 = blo(qu.y) * SC, q3 = bhi(qu.y) * SC;
    float q4 = blo(qu.z) * SC, q5 = bhi(qu.z) * SC, q6 = blo(qu.w) * SC, q7 = bhi(qu.w) * SC;
    const float* wep = We + c0 * 3;
    float g0, g1, g2;
    {
        float4 w0 = *(const float4*)(wep);
        float4 w1 = *(const float4*)(wep + 4);
        float4 w2 = *(const float4*)(wep + 8);
        float4 w3 = *(const float4*)(wep + 12);
        float4 w4 = *(const float4*)(wep + 16);
        float4 w5 = *(const float4*)(wep + 20);
        g0 = q0*w0.x + q1*w0.w + q2*w1.z + q3*w2.y + q4*w3.x + q5*w3.w + q6*w4.z + q7*w5.y;
        g1 = q0*w0.y + q1*w1.x + q2*w1.w + q3*w2.z + q4*w3.y + q5*w4.x + q6*w4.w + q7*w5.z;
        g2 = q0*w0.z + q1*w1.y + q2*w2.x + q3*w2.w + q4*w3.z + q5*w4.y + q6*w5.x + q7*w5.w;
    }
    g0 += __shfl_xor(g0, 1); g1 += __shfl_xor(g1, 1); g2 += __shfl_xor(g2, 1);
    g0 += __shfl_xor(g0, 2); g1 += __shfl_xor(g1, 2); g2 += __shfl_xor(g2, 2);

    int e0 = rowstart[n], e1 = rowstart[n + 1];
    int deg = e1 - e0;
    float ss = 0.f, S0 = 0.f, S1 = 0.f, S2 = 0.f;
    float o0 = 0.f, o1 = 0.f, o2 = 0.f, o3 = 0.f, o4 = 0.f, o5 = 0.f, o6 = 0.f, o7 = 0.f;

    if (deg > 0) {
        int iters = (deg + 3) >> 2;
        int eb = e0 + quarter;
        int elast = e1 - 1;
        int4 r0 = rec[min(eb, elast)];
        int4 r1 = rec[min(eb + 4, elast)];
        const u16* kvB = qkvs + 128 + (size_t)li * 16;
        uint4 kA = *(const uint4*)(kvB + (size_t)r0.x * 512);
        uint4 kB = *(const uint4*)(kvB + (size_t)r0.x * 512 + 8);
        for (int i = 0; i < iters; ++i) {
            int4 r2 = rec[min(eb + 4 * (i + 2), elast)];
            const u16* kp = kvB + (size_t)r1.x * 512;
            uint4 nA = *(const uint4*)(kp);
            uint4 nB = *(const uint4*)(kp + 8);
            // compute edge (r0, kA, kB)
            float part = q0 * blo(kA.x) + q1 * bhi(kA.x) + q2 * blo(kA.y) + q3 * bhi(kA.y)
                       + q4 * blo(kB.x) + q5 * bhi(kB.x) + q6 * blo(kB.y) + q7 * bhi(kB.y);
            part += __shfl_xor(part, 1);
            part += __shfl_xor(part, 2);
            float ea0 = __int_as_float(r0.y), ea1 = __int_as_float(r0.z), ea2 = __int_as_float(r0.w);
            float alpha = fmaf(ea2, g2, fmaf(ea1, g1, fmaf(ea0, g0, part)));
            float p = __expf(fminf(alpha, 80.f));
            p = (eb + 4 * i < e1) ? p : 0.f;
            o0 = fmaf(p, blo(kA.z), o0);
            o1 = fmaf(p, bhi(kA.z), o1);
            o2 = fmaf(p, blo(kA.w), o2);
            o3 = fmaf(p, bhi(kA.w), o3);
            o4 = fmaf(p, blo(kB.z), o4);
            o5 = fmaf(p, bhi(kB.z), o5);
            o6 = fmaf(p, blo(kB.w), o6);
            o7 = fmaf(p, bhi(kB.w), o7);
            ss += p;
            S0 = fmaf(p, ea0, S0);
            S1 = fmaf(p, ea1, S1);
            S2 = fmaf(p, ea2, S2);
            r0 = r1; r1 = r2; kA = nA; kB = nB;
        }
    }
    // combine the 4 quarter partials (exact additive)
    o0 += __shfl_xor(o0, 16); o1 += __shfl_xor(o1, 16); o2 += __shfl_xor(o2, 16); o3 += __shfl_xor(o3, 16);
    o4 += __shfl_xor(o4, 16); o5 += __shfl_xor(o5, 16); o6 += __shfl_xor(o6, 16); o7 += __shfl_xor(o7, 16);
    ss += __shfl_xor(ss, 16); S0 += __shfl_xor(S0, 16); S1 += __shfl_xor(S1, 16); S2 += __shfl_xor(S2, 16);
    o0 += __shfl_xor(o0, 32); o1 += __shfl_xor(o1, 32); o2 += __shfl_xor(o2, 32); o3 += __shfl_xor(o3, 32);
    o4 += __shfl_xor(o4, 32); o5 += __shfl_xor(o5, 32); o6 += __shfl_xor(o6, 32); o7 += __shfl_xor(o7, 32);
    ss += __shfl_xor(ss, 32); S0 += __shfl_xor(S0, 32); S1 += __shfl_xor(S1, 32); S2 += __shfl_xor(S2, 32);

    float inv = __builtin_amdgcn_rcpf(fmaxf(ss, 1e-16f));
    {   // add We . S per col (We reloaded — L1-hot)
        float4 w0 = *(const float4*)(wep);
        float4 w1 = *(const float4*)(wep + 4);
        float4 w2 = *(const float4*)(wep + 8);
        float4 w3 = *(const float4*)(wep + 12);
        float4 w4 = *(const float4*)(wep + 16);
        float4 w5 = *(const float4*)(wep + 20);
        o0 += w0.x * S0 + w0.y * S1 + w0.z * S2;
        o1 += w0.w * S0 + w1.x * S1 + w1.y * S2;
        o2 += w1.z * S0 + w1.w * S1 + w2.x * S2;
        o3 += w2.y * S0 + w2.z * S1 + w2.w * S2;
        o4 += w3.x * S0 + w3.y * S1 + w3.z * S2;
        o5 += w3.w * S0 + w4.x * S1 + w4.y * S2;
        o6 += w4.z * S0 + w4.w * S1 + w5.x * S2;
        o7 += w5.y * S0 + w5.z * S1 + w5.w * S2;
    }
    uint4 su = *(const uint4*)(qrow + 384 + c0);
    float r0v = fmaf(o0, inv, blo(su.x));
    float r1v = fmaf(o1, inv, bhi(su.x));
    float r2v = fmaf(o2, inv, blo(su.y));
    float r3v = fmaf(o3, inv, bhi(su.y));
    float r4v = fmaf(o4, inv, blo(su.z));
    float r5v = fmaf(o5, inv, bhi(su.z));
    float r6v = fmaf(o6, inv, blo(su.w));
    float r7v = fmaf(o7, inv, bhi(su.w));
    if (quarter == 0) {
        uint4 ou;
        ou.x = (u32)f2us(r0v) | ((u32)f2us(r1v) << 16);
        ou.y = (u32)f2us(r2v) | ((u32)f2us(r3v) << 16);
        ou.z = (u32)f2us(r4v) | ((u32)f2us(r5v) << 16);
        ou.w = (u32)f2us(r6v) | ((u32)f2us(r7v) << 16);
        *(uint4*)(out + (size_t)n * 128 + c0) = ou;
    }
}

// ---------------- launcher ----------------

extern "C" void kernel_launch(void* const* d_in, const int* in_sizes, int n_in,
                              void* d_out, int out_size, void* d_ws, size_t ws_size,
                              hipStream_t stream) {
    const float* x = (const float*)d_in[0];
    const int* ei = (const int*)d_in[1];
    const float* eattr = (const float*)d_in[2];
    const float* Wq1 = (const float*)d_in[3];
    const float* Wk1 = (const float*)d_in[4];
    const float* Wv1 = (const float*)d_in[5];
    const float* We1 = (const float*)d_in[6];
    const float* Ws1 = (const float*)d_in[7];
    const float* M1a = (const float*)d_in[8];
    const float* b1a = (const float*)d_in[9];
    const float* M1b = (const float*)d_in[10];
    const float* b1b = (const float*)d_in[11];
    const float* Wq2 = (const float*)d_in[12];
    const float* Wk2 = (const float*)d_in[13];
    const float* Wv2 = (const float*)d_in[14];
    const float* We2 = (const float*)d_in[15];
    const float* Ws2 = (const float*)d_in[16];
    const float* M2a = (const float*)d_in[17];
    const float* b2a = (const float*)d_in[18];
    const float* M2b = (const float*)d_in[19];
    const float* b2b = (const float*)d_in[20];
    const float* Wf1 = (const float*)d_in[21];
    const float* bf1 = (const float*)d_in[22];
    const float* Wf2 = (const float*)d_in[23];
    const float* bf2 = (const float*)d_in[24];

    char* ws = (char*)d_ws;
    size_t off = 0;
    auto alloc = [&](size_t bytes) -> void* {
        void* p = ws + off;
        off = (off + bytes + 255) & ~(size_t)255;
        return p;
    };
    int* deg = (int*)alloc((size_t)NN * 4);
    int* rowstart = (int*)alloc((size_t)(NN + 1) * 4);
    int* cursor = (int*)alloc((size_t)NN * 4);
    int* bsum = (int*)alloc((size_t)NB_SCAN * 4);
    int4* rec = (int4*)alloc((size_t)NE * 16);
    u16* QKVS = (u16*)alloc((size_t)NPAD * 512 * 2);
    u16* Ha = (u16*)alloc((size_t)NPAD * 128 * 2);
    // weight order: [Wq1 Wk1 Wv1 Ws1][Wq2 Wk2 Wv2 Ws2][M1a M1b][M2a M2b][Wf1 Wf2]
    u16* WB[14];
    const int wsz[14] = {16384, 16384, 16384, 16384, 16384, 16384, 16384,
                         16384, 16384, 16384, 16384, 16384, 16384, 8192};
    for (int i = 0; i < 14; ++i) WB[i] = (u16*)alloc((size_t)wsz[i] * 2);

    const int* srcv = ei;
    const int* dstv = ei + NE;

    // CSR build
    hipMemsetAsync(deg, 0, (size_t)NN * 4, stream);
    k_hist<<<(NE + 255) / 256, 256, 0, stream>>>(dstv, deg);
    k_scan1<<<NB_SCAN, 256, 0, stream>>>(deg, rowstart, bsum);
    k_scan2<<<1, 256, 0, stream>>>(bsum);
    k_scan3<<<NB_SCAN, 256, 0, stream>>>(bsum, rowstart, cursor);
    k_scatter<<<(NE + 255) / 256, 256, 0, stream>>>(srcv, dstv, eattr, cursor, rec);

    CvtTab tab;
    const float* wsrc[14] = {Wq1, Wk1, Wv1, Ws1, Wq2, Wk2, Wv2, Ws2,
                             M1a, M1b, M2a, M2b, Wf1, Wf2};
    for (int i = 0; i < 14; ++i) { tab.e[i].s = wsrc[i]; tab.e[i].d = WB[i]; tab.e[i].n = wsz[i]; }
    k_cvt_w<<<112, 256, 0, stream>>>(tab);

    dim3 blk(256);
    dim3 grd2(NPAD / 64, 2);   // column-split GEMM kernels
    dim3 grd(NPAD / 64);
    dim3 gconv(NN / 4);        // 12500

    // layer 1
    k_qkvs1<<<grd2, blk, 0, stream>>>(x, WB[0], QKVS);
    k_conv<<<gconv, blk, 0, stream>>>(rowstart, rec, QKVS, We1, Ha);            // H1 = Ha
    // MLP1 + layer-2 QKVS (H2 never hits HBM)
    k_mlp_qkvs<<<grd2, blk, 0, stream>>>(Ha, WB[8], b1a, b1b, WB[4], QKVS);
    k_conv<<<gconv, blk, 0, stream>>>(rowstart, rec, QKVS, We2, Ha);            // H3 = Ha
    // MLP2 + final MLP (H4 never hits HBM)
    k_mlp_final<<<grd, blk, 0, stream>>>(Ha, WB[10], b2a, b2b, WB[12], bf1, bf2, (float*)d_out);
}

// Round 12
// 412.145 us; speedup vs baseline: 1.0184x; 1.0184x over previous
//
#include <hip/hip_runtime.h>
#include <hip/hip_bf16.h>
#include <math.h>

// Problem constants (fixed by the reference)
#define NN 50000
#define NE 800000
#define NPAD 50048   // 3128 * 16 — tail-free GEMM tiles
#define NB_SCAN 196  // ceil(NN/256)

typedef unsigned short u16;
typedef unsigned int u32;
typedef __attribute__((ext_vector_type(8))) short short8;   // 8 bf16 (MFMA A/B frag)
typedef __attribute__((ext_vector_type(4))) float float4v;  // MFMA C/D frag

__device__ __forceinline__ float us2f(u16 u) { return __uint_as_float(((unsigned)u) << 16); }
__device__ __forceinline__ float blo(u32 u) { return __uint_as_float(u << 16); }
__device__ __forceinline__ float bhi(u32 u) { return __uint_as_float(u & 0xffff0000u); }
__device__ __forceinline__ u16 f2us(float f) {   // fp32 -> bf16 RNE
    unsigned x = __float_as_uint(f);
    return (u16)((x + 0x7FFFu + ((x >> 16) & 1u)) >> 16);
}
// tanh-gelu via sigmoid identity: 0.5*(1+tanh(u)) = sigmoid(2u)
__device__ __forceinline__ float gelu_f(float x) {
    float p = x * x;
    float t = x * fmaf(p, 0.0713548162726f, 1.5957691216057308f);  // 2u
    float e = __expf(-t);
    return x * __builtin_amdgcn_rcpf(1.0f + e);
}
// intra-wave LDS ordering fence (wave-private LDS; no cross-wave barriers anywhere)
__device__ __forceinline__ void lds_fence() {
    asm volatile("s_waitcnt lgkmcnt(0)" ::: "memory");
}

// ---- permuted-weight MFMA: WP holds B-frags contiguous per (tile, kblock) ----
// WP u16 layout: tile*2048 + q*512 + l*8 + j  <=>  W[tile*16 + (l&15)][q*32 + (l>>4)*8 + j]
__device__ __forceinline__ float4v mfma4p(const u16* __restrict__ WP, int tile, int l,
                                          short8 a0, short8 a1, short8 a2, short8 a3) {
    const short8* wp = (const short8*)WP + (size_t)tile * 256 + l;
    short8 b0 = wp[0], b1 = wp[64], b2 = wp[128], b3 = wp[192];
    float4v acc = {0.f, 0.f, 0.f, 0.f};
    acc = __builtin_amdgcn_mfma_f32_16x16x32_bf16(a0, b0, acc, 0, 0, 0);
    acc = __builtin_amdgcn_mfma_f32_16x16x32_bf16(a1, b1, acc, 0, 0, 0);
    acc = __builtin_amdgcn_mfma_f32_16x16x32_bf16(a2, b2, acc, 0, 0, 0);
    acc = __builtin_amdgcn_mfma_f32_16x16x32_bf16(a3, b3, acc, 0, 0, 0);
    return acc;
}

// ---------------- CSR build ----------------

__global__ void k_hist(const int* __restrict__ dstv, int* __restrict__ deg) {
    int e = blockIdx.x * blockDim.x + threadIdx.x;
    if (e < NE) atomicAdd(&deg[dstv[e]], 1);
}

__global__ __launch_bounds__(256) void k_scan1(const int* __restrict__ deg,
                                               int* __restrict__ rowstart,
                                               int* __restrict__ bsum) {
    __shared__ int wtot[4];
    int i = blockIdx.x * 256 + threadIdx.x;
    int lane = threadIdx.x & 63, w = threadIdx.x >> 6;
    int v = (i < NN) ? deg[i] : 0;
    int incl = v;
#pragma unroll
    for (int d = 1; d < 64; d <<= 1) {
        int tv = __shfl_up(incl, d);
        if (lane >= d) incl += tv;
    }
    if (lane == 63) wtot[w] = incl;
    __syncthreads();
    if (threadIdx.x == 0) {
        int s = 0;
#pragma unroll
        for (int j = 0; j < 4; ++j) { int t = wtot[j]; wtot[j] = s; s += t; }
        bsum[blockIdx.x] = s;
    }
    __syncthreads();
    if (i < NN) rowstart[i] = incl - v + wtot[w];
}

__global__ __launch_bounds__(256) void k_scan2(int* __restrict__ bsum) {
    __shared__ int wtot[4];
    int t = threadIdx.x;
    int lane = t & 63, w = t >> 6;
    int v = (t < NB_SCAN) ? bsum[t] : 0;
    int incl = v;
#pragma unroll
    for (int d = 1; d < 64; d <<= 1) {
        int tv = __shfl_up(incl, d);
        if (lane >= d) incl += tv;
    }
    if (lane == 63) wtot[w] = incl;
    __syncthreads();
    if (t == 0) {
        int s = 0;
#pragma unroll
        for (int j = 0; j < 4; ++j) { int tt = wtot[j]; wtot[j] = s; s += tt; }
    }
    __syncthreads();
    if (t < NB_SCAN) bsum[t] = incl - v + wtot[w];
}

__global__ void k_scan3(const int* __restrict__ bsum, int* __restrict__ rowstart,
                        int* __restrict__ cursor) {
    int i = blockIdx.x * 256 + threadIdx.x;
    if (i < NN) {
        int v = rowstart[i] + bsum[blockIdx.x];
        rowstart[i] = v;
        cursor[i] = v;
    }
    if (i == 0) rowstart[NN] = NE;
}

__global__ void k_scatter(const int* __restrict__ srcv, const int* __restrict__ dstv,
                          const float* __restrict__ eattr, int* __restrict__ cursor,
                          int4* __restrict__ rec) {
    int e = blockIdx.x * blockDim.x + threadIdx.x;
    if (e >= NE) return;
    int dst = dstv[e];
    int pos = atomicAdd(&cursor[dst], 1);
    int4 r;
    r.x = srcv[e];
    r.y = __float_as_int(eattr[e * 3 + 0]);
    r.z = __float_as_int(eattr[e * 3 + 1]);
    r.w = __float_as_int(eattr[e * 3 + 2]);
    rec[pos] = r;
}

// ---------------- weight fp32 -> bf16, permuted into B-frag order ----------------

struct CvtEnt { const float* s; u16* d; int n; };
struct CvtTab { CvtEnt e[14]; };
__global__ void k_cvt_w(CvtTab tab) {
    CvtEnt E = tab.e[blockIdx.x >> 3];
    int chunk = blockIdx.x & 7;
    int per = E.n >> 3;
    int lo = chunk * per, hi = lo + per;
    for (int o = lo + threadIdx.x; o < hi; o += blockDim.x) {
        int tile = o >> 11;
        int q = (o >> 9) & 3;
        int l = (o >> 3) & 63;
        int j = o & 7;
        int row = tile * 16 + (l & 15);
        int col = q * 32 + (l >> 4) * 8 + j;
        E.d[o] = f2us(E.s[row * 128 + col]);
    }
}

// padded We tables: WeP[c] = {We[c][0], We[c][1], We[c][2], 0}
__global__ void k_prep_we(const float* __restrict__ We1, const float* __restrict__ We2,
                          float4* __restrict__ WeP1, float4* __restrict__ WeP2) {
    int t = threadIdx.x;
    if (t < 128) {
        WeP1[t] = make_float4(We1[t * 3], We1[t * 3 + 1], We1[t * 3 + 2], 0.f);
    } else {
        int c = t - 128;
        WeP2[c] = make_float4(We2[c * 3], We2[c * 3 + 1], We2[c * 3 + 2], 0.f);
    }
}

// =============== barrier-free, single-wave GEMM chain kernels ===============
// Block = 1 wave = 16 rows. All staging intra-wave; no __syncthreads ever.

__device__ __forceinline__ void stage_plain(u16* buf, int kb, int m, int tt, float4v acc) {
#pragma unroll
    for (int r = 0; r < 4; ++r) buf[(kb * 4 + r) * 136 + tt * 16 + m] = f2us(acc[r]);
}
__device__ __forceinline__ void store128(const u16* buf, u16* dst, int r0w, int coff, int l) {
#pragma unroll
    for (int it = 0; it < 4; ++it) {
        int j = it * 64 + l;
        int row = j >> 4, col = (j & 15) * 8;
        *(uint4*)(dst + (size_t)(r0w + row) * 512 + coff + col) = *(const uint4*)&buf[row * 136 + col];
    }
}
__device__ __forceinline__ void read_frags(const u16* buf, int m, int kb,
                                           short8& f0, short8& f1, short8& f2, short8& f3) {
    const u16* p = buf + m * 136 + kb * 8;
    f0 = *(const short8*)(p);
    f1 = *(const short8*)(p + 32);
    f2 = *(const short8*)(p + 64);
    f3 = *(const short8*)(p + 96);
}

// g precompute: q tile (16x128 bf16, plain layout) resident in buf; lane l computes
// full head-reduction g[row=m][head=kb][j] = sum_d q[row][kb*32+d] * WeP[kb*32+d].j
__device__ __forceinline__ void compute_g(const u16* buf, const float4* __restrict__ WeP,
                                          float4* __restrict__ G, int r0w, int m, int kb) {
    const u16* qr = buf + m * 136 + kb * 32;
    short8 qv0 = *(const short8*)(qr);
    short8 qv1 = *(const short8*)(qr + 8);
    short8 qv2 = *(const short8*)(qr + 16);
    short8 qv3 = *(const short8*)(qr + 24);
    const float4* wp = WeP + kb * 32;
    float g0 = 0.f, g1 = 0.f, g2 = 0.f;
    const short8* qs[4] = {&qv0, &qv1, &qv2, &qv3};
#pragma unroll
    for (int b = 0; b < 4; ++b) {
        const u16* qq = (const u16*)qs[b];
#pragma unroll
        for (int d = 0; d < 8; ++d) {
            float qvf = us2f(qq[d]);
            float4 wv = wp[b * 8 + d];
            g0 = fmaf(qvf, wv.x, g0);
            g1 = fmaf(qvf, wv.y, g1);
            g2 = fmaf(qvf, wv.z, g2);
        }
    }
    G[(size_t)(r0w + m) * 4 + kb] = make_float4(g0, g1, g2, 0.f);
}

// kv staging: col c -> k at (c>>2)*8+(c&3), v at (c>>2)*8+4+(c&3)
// i.e. groups {k[4p..4p+3], v[4p..4p+3]} — conv lane li reads 32B at 128+li*16.

// ---------------- layer-1 QKVS GEMM (A = fp32 x; W permuted, 32 tiles) ----------------

__global__ __launch_bounds__(64, 4) void k_qkvs1(const float* __restrict__ Ain,
                                                 const u16* __restrict__ W,
                                                 const float4* __restrict__ WeP,
                                                 float4* __restrict__ G,
                                                 u16* __restrict__ QKVS) {
    __shared__ u16 my[16 * 136];
    int l = threadIdx.x;
    int m = l & 15, kb = l >> 4;
    int r0w = blockIdx.x * 16;

    short8 a0, a1, a2, a3;
    {
        const float* ap = Ain + (size_t)(r0w + m) * 128;
        bool ok = (r0w + m) < NN;
        short8* dsts[4] = {&a0, &a1, &a2, &a3};
#pragma unroll
        for (int i = 0; i < 4; ++i) {
            short8 r;
            if (ok) {
                const float* p = ap + (kb + i * 4) * 8;
                float4 f0 = *(const float4*)p;
                float4 f1 = *(const float4*)(p + 4);
                r[0]=(short)f2us(f0.x); r[1]=(short)f2us(f0.y); r[2]=(short)f2us(f0.z); r[3]=(short)f2us(f0.w);
                r[4]=(short)f2us(f1.x); r[5]=(short)f2us(f1.y); r[6]=(short)f2us(f1.z); r[7]=(short)f2us(f1.w);
            } else {
#pragma unroll
                for (int j = 0; j < 8; ++j) r[j] = 0;
            }
            *dsts[i] = r;
        }
    }

    // ---- q (tiles 0..7) + g ----
#pragma unroll
    for (int tt = 0; tt < 8; ++tt) stage_plain(my, kb, m, tt, mfma4p(W, tt, l, a0, a1, a2, a3));
    lds_fence();
    store128(my, QKVS, r0w, 0, l);
    compute_g(my, WeP, G, r0w, m, kb);
    lds_fence();
    // ---- kv-lo: k tiles 8..11 + v tiles 16..19 ----
#pragma unroll
    for (int tt = 0; tt < 4; ++tt) {
        float4v acc = mfma4p(W, 8 + tt, l, a0, a1, a2, a3);
        int c = tt * 32 + 8 * (m >> 2) + (m & 3);
#pragma unroll
        for (int r = 0; r < 4; ++r) my[(kb * 4 + r) * 136 + c] = f2us(acc[r]);
    }
#pragma unroll
    for (int tt = 0; tt < 4; ++tt) {
        float4v acc = mfma4p(W, 16 + tt, l, a0, a1, a2, a3);
        int c = tt * 32 + 8 * (m >> 2) + (m & 3) + 4;
#pragma unroll
        for (int r = 0; r < 4; ++r) my[(kb * 4 + r) * 136 + c] = f2us(acc[r]);
    }
    lds_fence();
    store128(my, QKVS, r0w, 128, l);
    lds_fence();
    // ---- kv-hi: k tiles 12..15 + v tiles 20..23 ----
#pragma unroll
    for (int tt = 0; tt < 4; ++tt) {
        float4v acc = mfma4p(W, 12 + tt, l, a0, a1, a2, a3);
        int c = tt * 32 + 8 * (m >> 2) + (m & 3);
#pragma unroll
        for (int r = 0; r < 4; ++r) my[(kb * 4 + r) * 136 + c] = f2us(acc[r]);
    }
#pragma unroll
    for (int tt = 0; tt < 4; ++tt) {
        float4v acc = mfma4p(W, 20 + tt, l, a0, a1, a2, a3);
        int c = tt * 32 + 8 * (m >> 2) + (m & 3) + 4;
#pragma unroll
        for (int r = 0; r < 4; ++r) my[(kb * 4 + r) * 136 + c] = f2us(acc[r]);
    }
    lds_fence();
    store128(my, QKVS, r0w, 256, l);
    lds_fence();
    // ---- s (tiles 24..31) ----
#pragma unroll
    for (int tt = 0; tt < 8; ++tt) stage_plain(my, kb, m, tt, mfma4p(W, 24 + tt, l, a0, a1, a2, a3));
    lds_fence();
    store128(my, QKVS, r0w, 384, l);
}

// ---------------- fused MLP + next-layer QKVS (single wave) ----------------

__global__ __launch_bounds__(64, 4) void k_mlp_qkvs(const u16* __restrict__ Ain,
                                                    const u16* __restrict__ Wm,
                                                    const float* __restrict__ bias1,
                                                    const float* __restrict__ bias2,
                                                    const u16* __restrict__ Wq,
                                                    const float4* __restrict__ WeP,
                                                    float4* __restrict__ G,
                                                    u16* __restrict__ QKVS) {
    __shared__ u16 sh[16 * 136];
    __shared__ u16 t1[16 * 136];
    int l = threadIdx.x;
    int m = l & 15, kb = l >> 4;
    int r0w = blockIdx.x * 16;

    const short8* arow = (const short8*)(Ain + (size_t)(r0w + m) * 128);
    short8 a0 = arow[kb], a1 = arow[kb + 4], a2 = arow[kb + 8], a3 = arow[kb + 12];
    {   // stage A (residual source), linear rows
        u16* p = sh + m * 136 + kb * 8;
        *(short8*)(p) = a0;
        *(short8*)(p + 32) = a1;
        *(short8*)(p + 64) = a2;
        *(short8*)(p + 96) = a3;
    }
    // GEMM1 -> t1 (gelu)
#pragma unroll
    for (int tt = 0; tt < 8; ++tt) {
        float4v acc = mfma4p(Wm, tt, l, a0, a1, a2, a3);
        float bv = bias1[tt * 16 + m];
#pragma unroll
        for (int r = 0; r < 4; ++r)
            t1[(kb * 4 + r) * 136 + tt * 16 + m] = f2us(gelu_f(acc[r] + bv));
    }
    lds_fence();
    short8 c0, c1, c2, c3;
    read_frags(t1, m, kb, c0, c1, c2, c3);
    // GEMM2 + residual -> sh becomes H2 (owner-lane RMW)
#pragma unroll
    for (int tt = 0; tt < 8; ++tt) {
        float4v acc = mfma4p(Wm + 16384, tt, l, c0, c1, c2, c3);
        float bv = bias2[tt * 16 + m];
#pragma unroll
        for (int r = 0; r < 4; ++r) {
            int idx = (kb * 4 + r) * 136 + tt * 16 + m;
            sh[idx] = f2us(gelu_f(acc[r] + bv) + us2f(sh[idx]));
        }
    }
    lds_fence();
    short8 h0, h1, h2, h3;
    read_frags(sh, m, kb, h0, h1, h2, h3);

    // ---- q (tiles 0..7) + g ----
#pragma unroll
    for (int tt = 0; tt < 8; ++tt) stage_plain(t1, kb, m, tt, mfma4p(Wq, tt, l, h0, h1, h2, h3));
    lds_fence();
    store128(t1, QKVS, r0w, 0, l);
    compute_g(t1, WeP, G, r0w, m, kb);
    lds_fence();
    // ---- kv-lo ----
#pragma unroll
    for (int tt = 0; tt < 4; ++tt) {
        float4v acc = mfma4p(Wq, 8 + tt, l, h0, h1, h2, h3);
        int c = tt * 32 + 8 * (m >> 2) + (m & 3);
#pragma unroll
        for (int r = 0; r < 4; ++r) t1[(kb * 4 + r) * 136 + c] = f2us(acc[r]);
    }
#pragma unroll
    for (int tt = 0; tt < 4; ++tt) {
        float4v acc = mfma4p(Wq, 16 + tt, l, h0, h1, h2, h3);
        int c = tt * 32 + 8 * (m >> 2) + (m & 3) + 4;
#pragma unroll
        for (int r = 0; r < 4; ++r) t1[(kb * 4 + r) * 136 + c] = f2us(acc[r]);
    }
    lds_fence();
    store128(t1, QKVS, r0w, 128, l);
    lds_fence();
    // ---- kv-hi ----
#pragma unroll
    for (int tt = 0; tt < 4; ++tt) {
        float4v acc = mfma4p(Wq, 12 + tt, l, h0, h1, h2, h3);
        int c = tt * 32 + 8 * (m >> 2) + (m & 3);
#pragma unroll
        for (int r = 0; r < 4; ++r) t1[(kb * 4 + r) * 136 + c] = f2us(acc[r]);
    }
#pragma unroll
    for (int tt = 0; tt < 4; ++tt) {
        float4v acc = mfma4p(Wq, 20 + tt, l, h0, h1, h2, h3);
        int c = tt * 32 + 8 * (m >> 2) + (m & 3) + 4;
#pragma unroll
        for (int r = 0; r < 4; ++r) t1[(kb * 4 + r) * 136 + c] = f2us(acc[r]);
    }
    lds_fence();
    store128(t1, QKVS, r0w, 256, l);
    lds_fence();
    // ---- s (tiles 24..31) ----
#pragma unroll
    for (int tt = 0; tt < 8; ++tt) stage_plain(t1, kb, m, tt, mfma4p(Wq, 24 + tt, l, h0, h1, h2, h3));
    lds_fence();
    store128(t1, QKVS, r0w, 384, l);
}

// ---------------- fused MLP + final MLP (single wave) ----------------

__global__ __launch_bounds__(64, 4) void k_mlp_final(const u16* __restrict__ Ain,
                                                     const u16* __restrict__ Wm,
                                                     const float* __restrict__ bias1,
                                                     const float* __restrict__ bias2,
                                                     const u16* __restrict__ Wf,
                                                     const float* __restrict__ bf1,
                                                     const float* __restrict__ bf2,
                                                     float* __restrict__ outp) {
    __shared__ u16 sh[16 * 136];
    __shared__ u16 t1[16 * 136];
    int l = threadIdx.x;
    int m = l & 15, kb = l >> 4;
    int r0w = blockIdx.x * 16;

    const short8* arow = (const short8*)(Ain + (size_t)(r0w + m) * 128);
    short8 a0 = arow[kb], a1 = arow[kb + 4], a2 = arow[kb + 8], a3 = arow[kb + 12];
    {
        u16* p = sh + m * 136 + kb * 8;
        *(short8*)(p) = a0;
        *(short8*)(p + 32) = a1;
        *(short8*)(p + 64) = a2;
        *(short8*)(p + 96) = a3;
    }
#pragma unroll
    for (int tt = 0; tt < 8; ++tt) {
        float4v acc = mfma4p(Wm, tt, l, a0, a1, a2, a3);
        float bv = bias1[tt * 16 + m];
#pragma unroll
        for (int r = 0; r < 4; ++r)
            t1[(kb * 4 + r) * 136 + tt * 16 + m] = f2us(gelu_f(acc[r] + bv));
    }
    lds_fence();
    short8 c0, c1, c2, c3;
    read_frags(t1, m, kb, c0, c1, c2, c3);
#pragma unroll
    for (int tt = 0; tt < 8; ++tt) {
        float4v acc = mfma4p(Wm + 16384, tt, l, c0, c1, c2, c3);
        float bv = bias2[tt * 16 + m];
#pragma unroll
        for (int r = 0; r < 4; ++r) {
            int idx = (kb * 4 + r) * 136 + tt * 16 + m;
            sh[idx] = f2us(gelu_f(acc[r] + bv) + us2f(sh[idx]));
        }
    }
    lds_fence();
    short8 h0, h1, h2, h3;
    read_frags(sh, m, kb, h0, h1, h2, h3);
    // G3 = gelu(H4@Wf1+bf1) -> t1
#pragma unroll
    for (int tt = 0; tt < 8; ++tt) {
        float4v acc = mfma4p(Wf, tt, l, h0, h1, h2, h3);
        float bv = bf1[tt * 16 + m];
#pragma unroll
        for (int r = 0; r < 4; ++r)
            t1[(kb * 4 + r) * 136 + tt * 16 + m] = f2us(gelu_f(acc[r] + bv));
    }
    lds_fence();
    short8 f0, f1, f2, f3;
    read_frags(t1, m, kb, f0, f1, f2, f3);
    lds_fence();
    // G4 = gelu(G3@Wf2+bf2), 64 cols -> t1
#pragma unroll
    for (int tt = 0; tt < 4; ++tt) {
        float4v acc = mfma4p(Wf + 16384, tt, l, f0, f1, f2, f3);
        float bv = bf2[tt * 16 + m];
#pragma unroll
        for (int r = 0; r < 4; ++r)
            t1[(kb * 4 + r) * 136 + tt * 16 + m] = f2us(gelu_f(acc[r] + bv));
    }
    lds_fence();
#pragma unroll
    for (int it = 0; it < 2; ++it) {
        int j = it * 64 + l;
        int row = j >> 3, col = (j & 7) * 8;
        int grow = r0w + row;
        if (grow < NN) {
            uint4 pk = *(const uint4*)&t1[row * 136 + col];
            const u16* pv = (const u16*)&pk;
            float* po = outp + (size_t)grow * 64 + col;
            float4 o0 = {us2f(pv[0]), us2f(pv[1]), us2f(pv[2]), us2f(pv[3])};
            float4 o1 = {us2f(pv[4]), us2f(pv[5]), us2f(pv[6]), us2f(pv[7])};
            *(float4*)po = o0;
            *(float4*)(po + 4) = o1;
        }
    }
}

// ---------------- TransformerConv: 4 edges/wave, 8 cols/lane, pipelined gather ----------------
// g precomputed per (node, head); epilogue uses padded WeP.

__global__ __launch_bounds__(256) void k_conv(const int* __restrict__ rowstart,
                                              const int4* __restrict__ rec,
                                              const u16* __restrict__ qkvs,
                                              const float4* __restrict__ WeP,
                                              const float4* __restrict__ G,
                                              u16* __restrict__ out) {
    int n = blockIdx.x * 4 + (threadIdx.x >> 6);
    int l = threadIdx.x & 63;
    int quarter = l >> 4;
    int li = l & 15;
    int c0 = li * 8;
    const u16* qrow = qkvs + (size_t)n * 512;
    uint4 qu = *(const uint4*)(qrow + c0);
    const float SC = 0.17677669529663687f;
    float q0 = blo(qu.x) * SC, q1 = bhi(qu.x) * SC, q2 = blo(qu.y) * SC, q3 = bhi(qu.y) * SC;
    float q4 = blo(qu.z) * SC, q5 = bhi(qu.z) * SC, q6 = blo(qu.w) * SC, q7 = bhi(qu.w) * SC;
    float4 gg = G[(size_t)n * 4 + (li >> 2)];
    float g0 = gg.x * SC, g1 = gg.y * SC, g2 = gg.z * SC;

    int e0 = rowstart[n], e1 = rowstart[n + 1];
    int deg = e1 - e0;
    float ss = 0.f, S0 = 0.f, S1 = 0.f, S2 = 0.f;
    float o0 = 0.f, o1 = 0.f, o2 = 0.f, o3 = 0.f, o4 = 0.f, o5 = 0.f, o6 = 0.f, o7 = 0.f;

    if (deg > 0) {
        int iters = (deg + 3) >> 2;
        int eb = e0 + quarter;
        int elast = e1 - 1;
        int4 r0 = rec[min(eb, elast)];
        int4 r1 = rec[min(eb + 4, elast)];
        const u16* kvB = qkvs + 128 + (size_t)li * 16;
        uint4 kA = *(const uint4*)(kvB + (size_t)r0.x * 512);
        uint4 kB = *(const uint4*)(kvB + (size_t)r0.x * 512 + 8);
        for (int i = 0; i < iters; ++i) {
            int4 r2 = rec[min(eb + 4 * (i + 2), elast)];
            const u16* kp = kvB + (size_t)r1.x * 512;
            uint4 nA = *(const uint4*)(kp);
            uint4 nB = *(const uint4*)(kp + 8);
            float part = q0 * blo(kA.x) + q1 * bhi(kA.x) + q2 * blo(kA.y) + q3 * bhi(kA.y)
                       + q4 * blo(kB.x) + q5 * bhi(kB.x) + q6 * blo(kB.y) + q7 * bhi(kB.y);
            part += __shfl_xor(part, 1);
            part += __shfl_xor(part, 2);
            float ea0 = __int_as_float(r0.y), ea1 = __int_as_float(r0.z), ea2 = __int_as_float(r0.w);
            float alpha = fmaf(ea2, g2, fmaf(ea1, g1, fmaf(ea0, g0, part)));
            float p = __expf(fminf(alpha, 80.f));
            p = (eb + 4 * i < e1) ? p : 0.f;
            o0 = fmaf(p, blo(kA.z), o0);
            o1 = fmaf(p, bhi(kA.z), o1);
            o2 = fmaf(p, blo(kA.w), o2);
            o3 = fmaf(p, bhi(kA.w), o3);
            o4 = fmaf(p, blo(kB.z), o4);
            o5 = fmaf(p, bhi(kB.z), o5);
            o6 = fmaf(p, blo(kB.w), o6);
            o7 = fmaf(p, bhi(kB.w), o7);
            ss += p;
            S0 = fmaf(p, ea0, S0);
            S1 = fmaf(p, ea1, S1);
            S2 = fmaf(p, ea2, S2);
            r0 = r1; r1 = r2; kA = nA; kB = nB;
        }
    }
    // combine the 4 quarter partials (exact additive)
    o0 += __shfl_xor(o0, 16); o1 += __shfl_xor(o1, 16); o2 += __shfl_xor(o2, 16); o3 += __shfl_xor(o3, 16);
    o4 += __shfl_xor(o4, 16); o5 += __shfl_xor(o5, 16); o6 += __shfl_xor(o6, 16); o7 += __shfl_xor(o7, 16);
    ss += __shfl_xor(ss, 16); S0 += __shfl_xor(S0, 16); S1 += __shfl_xor(S1, 16); S2 += __shfl_xor(S2, 16);
    o0 += __shfl_xor(o0, 32); o1 += __shfl_xor(o1, 32); o2 += __shfl_xor(o2, 32); o3 += __shfl_xor(o3, 32);
    o4 += __shfl_xor(o4, 32); o5 += __shfl_xor(o5, 32); o6 += __shfl_xor(o6, 32); o7 += __shfl_xor(o7, 32);
    ss += __shfl_xor(ss, 32); S0 += __shfl_xor(S0, 32); S1 += __shfl_xor(S1, 32); S2 += __shfl_xor(S2, 32);

    if (quarter == 0) {
        float inv = __builtin_amdgcn_rcpf(fmaxf(ss, 1e-16f));
        float4 w0 = WeP[c0 + 0], w1 = WeP[c0 + 1], w2 = WeP[c0 + 2], w3 = WeP[c0 + 3];
        float4 w4 = WeP[c0 + 4], w5 = WeP[c0 + 5], w6 = WeP[c0 + 6], w7 = WeP[c0 + 7];
        o0 += w0.x * S0 + w0.y * S1 + w0.z * S2;
        o1 += w1.x * S0 + w1.y * S1 + w1.z * S2;
        o2 += w2.x * S0 + w2.y * S1 + w2.z * S2;
        o3 += w3.x * S0 + w3.y * S1 + w3.z * S2;
        o4 += w4.x * S0 + w4.y * S1 + w4.z * S2;
        o5 += w5.x * S0 + w5.y * S1 + w5.z * S2;
        o6 += w6.x * S0 + w6.y * S1 + w6.z * S2;
        o7 += w7.x * S0 + w7.y * S1 + w7.z * S2;
        uint4 su = *(const uint4*)(qrow + 384 + c0);
        float r0v = fmaf(o0, inv, blo(su.x));
        float r1v = fmaf(o1, inv, bhi(su.x));
        float r2v = fmaf(o2, inv, blo(su.y));
        float r3v = fmaf(o3, inv, bhi(su.y));
        float r4v = fmaf(o4, inv, blo(su.z));
        float r5v = fmaf(o5, inv, bhi(su.z));
        float r6v = fmaf(o6, inv, blo(su.w));
        float r7v = fmaf(o7, inv, bhi(su.w));
        uint4 ou;
        ou.x = (u32)f2us(r0v) | ((u32)f2us(r1v) << 16);
        ou.y = (u32)f2us(r2v) | ((u32)f2us(r3v) << 16);
        ou.z = (u32)f2us(r4v) | ((u32)f2us(r5v) << 16);
        ou.w = (u32)f2us(r6v) | ((u32)f2us(r7v) << 16);
        *(uint4*)(out + (size_t)n * 128 + c0) = ou;
    }
}

// ---------------- launcher ----------------

extern "C" void kernel_launch(void* const* d_in, const int* in_sizes, int n_in,
                              void* d_out, int out_size, void* d_ws, size_t ws_size,
                              hipStream_t stream) {
    const float* x = (const float*)d_in[0];
    const int* ei = (const int*)d_in[1];
    const float* eattr = (const float*)d_in[2];
    const float* Wq1 = (const float*)d_in[3];
    const float* Wk1 = (const float*)d_in[4];
    const float* Wv1 = (const float*)d_in[5];
    const float* We1 = (const float*)d_in[6];
    const float* Ws1 = (const float*)d_in[7];
    const float* M1a = (const float*)d_in[8];
    const float* b1a = (const float*)d_in[9];
    const float* M1b = (const float*)d_in[10];
    const float* b1b = (const float*)d_in[11];
    const float* Wq2 = (const float*)d_in[12];
    const float* Wk2 = (const float*)d_in[13];
    const float* Wv2 = (const float*)d_in[14];
    const float* We2 = (const float*)d_in[15];
    const float* Ws2 = (const float*)d_in[16];
    const float* M2a = (const float*)d_in[17];
    const float* b2a = (const float*)d_in[18];
    const float* M2b = (const float*)d_in[19];
    const float* b2b = (const float*)d_in[20];
    const float* Wf1 = (const float*)d_in[21];
    const float* bf1 = (const float*)d_in[22];
    const float* Wf2 = (const float*)d_in[23];
    const float* bf2 = (const float*)d_in[24];

    char* ws = (char*)d_ws;
    size_t off = 0;
    auto alloc = [&](size_t bytes) -> void* {
        void* p = ws + off;
        off = (off + bytes + 255) & ~(size_t)255;
        return p;
    };
    int* deg = (int*)alloc((size_t)NN * 4);
    int* rowstart = (int*)alloc((size_t)(NN + 1) * 4);
    int* cursor = (int*)alloc((size_t)NN * 4);
    int* bsum = (int*)alloc((size_t)NB_SCAN * 4);
    int4* rec = (int4*)alloc((size_t)NE * 16);
    u16* QKVS = (u16*)alloc((size_t)NPAD * 512 * 2);
    u16* Ha = (u16*)alloc((size_t)NPAD * 128 * 2);
    float4* G = (float4*)alloc((size_t)NPAD * 4 * 16);
    float4* WeP1 = (float4*)alloc(128 * 16);
    float4* WeP2 = (float4*)alloc(128 * 16);
    // weight order: [Wq1 Wk1 Wv1 Ws1][Wq2 Wk2 Wv2 Ws2][M1a M1b][M2a M2b][Wf1 Wf2]
    u16* WB[14];
    const int wsz[14] = {16384, 16384, 16384, 16384, 16384, 16384, 16384,
                         16384, 16384, 16384, 16384, 16384, 16384, 8192};
    for (int i = 0; i < 14; ++i) WB[i] = (u16*)alloc((size_t)wsz[i] * 2);

    const int* srcv = ei;
    const int* dstv = ei + NE;

    // CSR build
    hipMemsetAsync(deg, 0, (size_t)NN * 4, stream);
    k_hist<<<(NE + 255) / 256, 256, 0, stream>>>(dstv, deg);
    k_scan1<<<NB_SCAN, 256, 0, stream>>>(deg, rowstart, bsum);
    k_scan2<<<1, 256, 0, stream>>>(bsum);
    k_scan3<<<NB_SCAN, 256, 0, stream>>>(bsum, rowstart, cursor);
    k_scatter<<<(NE + 255) / 256, 256, 0, stream>>>(srcv, dstv, eattr, cursor, rec);

    CvtTab tab;
    const float* wsrc[14] = {Wq1, Wk1, Wv1, Ws1, Wq2, Wk2, Wv2, Ws2,
                             M1a, M1b, M2a, M2b, Wf1, Wf2};
    for (int i = 0; i < 14; ++i) { tab.e[i].s = wsrc[i]; tab.e[i].d = WB[i]; tab.e[i].n = wsz[i]; }
    k_cvt_w<<<112, 256, 0, stream>>>(tab);
    k_prep_we<<<1, 256, 0, stream>>>(We1, We2, WeP1, WeP2);

    dim3 gg(NPAD / 16);        // 3128 single-wave blocks
    dim3 gconv(NN / 4);        // 12500

    // layer 1
    k_qkvs1<<<gg, 64, 0, stream>>>(x, WB[0], WeP1, G, QKVS);
    k_conv<<<gconv, 256, 0, stream>>>(rowstart, rec, QKVS, WeP1, G, Ha);        // H1 = Ha
    // MLP1 + layer-2 QKVS (H2 never hits HBM); also g for conv2
    k_mlp_qkvs<<<gg, 64, 0, stream>>>(Ha, WB[8], b1a, b1b, WB[4], WeP2, G, QKVS);
    k_conv<<<gconv, 256, 0, stream>>>(rowstart, rec, QKVS, WeP2, G, Ha);        // H3 = Ha
    // MLP2 + final MLP (H4 never hits HBM)
    k_mlp_final<<<gg, 64, 0, stream>>>(Ha, WB[10], b2a, b2b, WB[12], bf1, bf2, (float*)d_out);
}